// Round 14
// baseline (1181.985 us; speedup 1.0000x reference)
//
#include <hip/hip_runtime.h>
#include <hip/hip_bf16.h>

// GATv2 x3 layers, MI355X. f32 in/out; edge_index int32.
// R14: k_fga = score + softmax + aggregate fused, block per 3 nodes
// (contiguous CSR slice). Phase 1 is the verbatim R12 k_score thread body
// (VGPR-64 codegen) writing exp(score) to LDS; phase 2 aggregates with
// L1/L2-hot xs rows; phase 3 head-mean+bias+ELU. Kills wP round-trip and
// one dispatch per layer. k_xl separate (R12 structure — R13's per-block
// GEMM fusion had worse Wl reuse, neutral).

#define NN 10000    // nodes
#define NE 200000   // edges
#define ND 128      // node dim (layer 0 input)
#define ED 16       // edge dim
#define CD 64      // conv dim (per head)
#define NH 5        // heads
#define HC 320      // NH*CD
#define NEG 0.2f
#define NPB 3       // nodes per k_fga block
#define NB 3334     // ceil(NN/NPB)
#define SWZ 417     // ceil(NB/8): XCD swizzle stride (8*417=3336 blocks)
#define MAXP 384    // max positions/block (actual ~63+-8 for this input)

// ---- CSR build: count ----
__global__ void k_count(const int* __restrict__ dst, int* __restrict__ deg) {
  int e = blockIdx.x * blockDim.x + threadIdx.x;
  if (e >= NE) return;
  atomicAdd(&deg[dst[e]], 1);
}

// ---- CSR build: exclusive scan (single block, 1024 threads x 10 elems) ----
__global__ __launch_bounds__(1024) void k_scan(const int* __restrict__ deg,
                                               int* __restrict__ rowptr) {
  __shared__ int part[1024];
  int t = threadIdx.x;
  int base = t * 10;
  int local[10];
  int s = 0;
  #pragma unroll
  for (int j = 0; j < 10; j++) {
    int i = base + j;
    local[j] = (i < NN) ? deg[i] : 0;
    s += local[j];
  }
  part[t] = s;
  __syncthreads();
  for (int off = 1; off < 1024; off <<= 1) {
    int v = (t >= off) ? part[t - off] : 0;
    __syncthreads();
    part[t] += v;
    __syncthreads();
  }
  int prefix = (t > 0) ? part[t - 1] : 0;
  #pragma unroll
  for (int j = 0; j < 10; j++) {
    int i = base + j;
    if (i < NN) rowptr[i] = prefix;
    prefix += local[j];
  }
  if (t == 1023) rowptr[NN] = prefix;
}

// ---- CSR build: fill ----
__global__ void k_fill(const int* __restrict__ ei, const int* __restrict__ rowptr,
                       int* __restrict__ cursor, int* __restrict__ csr_eid,
                       int* __restrict__ csr_src) {
  int e = blockIdx.x * blockDim.x + threadIdx.x;
  if (e >= NE) return;
  int d = ei[NE + e];
  int slot = atomicAdd(&cursor[d], 1);
  int pos = rowptr[d] + slot;
  csr_eid[pos] = e;
  csr_src[pos] = ei[e];
}

// ---- loop_attr = mean of incoming edge_attr (gather, wave per node) ----
__global__ __launch_bounds__(256) void k_loopattr(const int* __restrict__ csr_eid,
                                                  const int* __restrict__ rowptr,
                                                  const float* __restrict__ eattr,
                                                  float* __restrict__ loop_attr) {
  int wave = threadIdx.x >> 6, lane = threadIdx.x & 63;
  int d = blockIdx.x * 4 + wave;
  if (d >= NN) return;
  int g = lane >> 4, k = lane & 15;
  int b = rowptr[d], n = rowptr[d + 1] - b;
  float s = 0.f;
  for (int i = g; i < n; i += 4)
    s += eattr[(size_t)csr_eid[b + i] * ED + k];
  s += __shfl_xor(s, 16, 64);
  s += __shfl_xor(s, 32, 64);
  if (g == 0) loop_attr[d * ED + k] = s / fmaxf((float)n, 1.0f);
}

// ---- ea_csr[p] = edge attrs permuted into CSR order (real edges only) ----
__global__ void k_eacsr(const int* __restrict__ csr_eid, const float* __restrict__ eattr,
                        float* __restrict__ ea_csr) {
  int idx = blockIdx.x * blockDim.x + threadIdx.x;  // (p, quad)
  if (idx >= NE * 4) return;
  int p = idx >> 2, q = idx & 3;
  const float4* sp = (const float4*)(eattr + (size_t)csr_eid[p] * ED);
  ((float4*)(ea_csr + (size_t)p * ED))[q] = sp[q];
}

// ---- WeT for all 3 layers in one dispatch ----
__global__ void k_wet3(const float* __restrict__ We0, const float* __restrict__ We1,
                       const float* __restrict__ We2, float* __restrict__ WeT) {
  int i = blockIdx.x * blockDim.x + threadIdx.x;
  if (i >= 3 * ED * HC) return;
  int l = i / (ED * HC), r = i % (ED * HC);
  int hc = r >> 4, k = r & 15;
  const float* src = (l == 0) ? We0 : (l == 1) ? We1 : We2;
  WeT[i] = src[k * HC + hc];
}

// ---- xl = h @ Wl + bl  (no LDS; h rows via uniform broadcast loads) ----
template <int D>
__global__ __launch_bounds__(320) void k_xl(const float* __restrict__ h,
                                            const float* __restrict__ Wl,
                                            const float* __restrict__ bl,
                                            float* __restrict__ xl) {
  constexpr int NP = 8;
  int node0 = blockIdx.x * NP;
  int t = threadIdx.x;  // output column 0..319
  float acc[NP];
  #pragma unroll
  for (int i = 0; i < NP; i++) acc[i] = 0.f;
  for (int k = 0; k < D; k += 4) {
    float w0 = Wl[(k + 0) * HC + t];
    float w1 = Wl[(k + 1) * HC + t];
    float w2 = Wl[(k + 2) * HC + t];
    float w3 = Wl[(k + 3) * HC + t];
    #pragma unroll
    for (int i = 0; i < NP; i++) {
      float4 hv = *(const float4*)(h + (size_t)(node0 + i) * D + k);
      acc[i] += hv.x * w0 + hv.y * w1 + hv.z * w2 + hv.w * w3;
    }
  }
  float bv = bl[t];
  #pragma unroll
  for (int i = 0; i < NP; i++)
    xl[(size_t)(node0 + i) * HC + t] = acc[i] + bv;
}

__device__ __forceinline__ float dot4(float4 a, float4 b) {
  return a.x * b.x + a.y * b.y + a.z * b.z + a.w * b.w;
}

// ---- fused GAT layer: block per NPB nodes (contiguous CSR slice) ----
// phase 1: scores (wave=head, lane=position; R12 k_score body) -> LDS
// phase 2: aggregate per node (wave=head, lane=channel; xs L1/L2-hot)
// phase 3: head-mean + bias + ELU -> out (64-wide)
__global__ __launch_bounds__(320) void k_fga(
    const int* __restrict__ csr_src, const int* __restrict__ rowptr,
    const float* __restrict__ ea_csr, const float* __restrict__ loop_attr,
    const float* __restrict__ xl, const float* __restrict__ WeT,
    const float* __restrict__ att, const float* __restrict__ bias,
    float* __restrict__ out) {
  __shared__ float s_w[NH][MAXP];
  __shared__ float s_v[NH][NPB][CD];
  int bid = blockIdx.x;
  int lb = (bid & 7) * SWZ + (bid >> 3);  // contiguous block range per XCD
  if (lb >= NB) return;
  int node0 = lb * NPB;
  int nnodes = min(NPB, NN - node0);
  int r0 = rowptr[node0];
  int rEnd = rowptr[node0 + nnodes];
  int rb1 = (nnodes > 1) ? rowptr[node0 + 1] : rEnd;
  int rb2 = (nnodes > 2) ? rowptr[node0 + 2] : rEnd;
  int n_real = rEnd - r0;
  int ntot = n_real + nnodes;

  int h = threadIdx.x >> 6, lane = threadIdx.x & 63;
  const float* wrow = WeT + h * CD * ED;
  const float* arow = att + h * CD;

  // ---- phase 1: scores ----
  for (int pos = lane; pos < ntot; pos += 64) {
    int s, d;
    const float* ea;
    if (pos < n_real) {
      int p = r0 + pos;
      s = csr_src[p];
      d = node0 + (p >= rb1) + (p >= rb2);
      ea = ea_csr + (size_t)p * ED;
    } else {
      int j = pos - n_real;
      s = d = node0 + j;
      ea = loop_attr + (size_t)(node0 + j) * ED;
    }
    float4 ea4[4];
    {
      const float4* q = (const float4*)ea;
      ea4[0] = q[0]; ea4[1] = q[1]; ea4[2] = q[2]; ea4[3] = q[3];
    }
    const float* xsrow = xl + (size_t)s * HC + h * CD;
    const float* xdrow = xl + (size_t)d * HC + h * CD;
    float sc = 0.f;
    #pragma unroll 4
    for (int cb = 0; cb < CD; cb += 4) {  // 16 iterations (R12 body)
      float4 xs4 = *(const float4*)(xsrow + cb);
      float4 xd4 = *(const float4*)(xdrow + cb);
      const float4* w0 = (const float4*)(wrow + (cb + 0) * ED);
      const float4* w1 = (const float4*)(wrow + (cb + 1) * ED);
      const float4* w2 = (const float4*)(wrow + (cb + 2) * ED);
      const float4* w3 = (const float4*)(wrow + (cb + 3) * ED);
      float z0 = xs4.x + xd4.x + dot4(ea4[0], w0[0]) + dot4(ea4[1], w0[1]) +
                 dot4(ea4[2], w0[2]) + dot4(ea4[3], w0[3]);
      float z1 = xs4.y + xd4.y + dot4(ea4[0], w1[0]) + dot4(ea4[1], w1[1]) +
                 dot4(ea4[2], w1[2]) + dot4(ea4[3], w1[3]);
      float z2 = xs4.z + xd4.z + dot4(ea4[0], w2[0]) + dot4(ea4[1], w2[1]) +
                 dot4(ea4[2], w2[2]) + dot4(ea4[3], w2[3]);
      float z3 = xs4.w + xd4.w + dot4(ea4[0], w3[0]) + dot4(ea4[1], w3[1]) +
                 dot4(ea4[2], w3[2]) + dot4(ea4[3], w3[3]);
      z0 *= (z0 > 0.f) ? 1.0f : NEG;
      z1 *= (z1 > 0.f) ? 1.0f : NEG;
      z2 *= (z2 > 0.f) ? 1.0f : NEG;
      z3 *= (z3 > 0.f) ? 1.0f : NEG;
      float4 a4 = *(const float4*)(arow + cb);
      sc += a4.x * z0 + a4.y * z1 + a4.z * z2 + a4.w * z3;
    }
    sc = fminf(fmaxf(sc, -60.f), 60.f);
    if (pos < MAXP) s_w[h][pos] = __expf(sc);
  }
  __syncthreads();

  // ---- phase 2: aggregate (wave=head, lane=channel) ----
  const float* xlh = xl + h * CD + lane;
  #pragma unroll
  for (int j = 0; j < NPB; j++) {
    if (j >= nnodes) break;
    int d = node0 + j;
    int pj0 = ((j == 0) ? r0 : (j == 1) ? rb1 : rb2) - r0;
    int pj1 = ((j == 0) ? rb1 : (j == 1) ? rb2 : rEnd) - r0;
    float wS = s_w[h][n_real + j];
    float dn = wS;
    float acc = wS * xlh[(size_t)d * HC];
    int p = pj0;
    for (; p + 4 <= pj1; p += 4) {
      int s0 = csr_src[r0 + p], s1 = csr_src[r0 + p + 1];
      int s2 = csr_src[r0 + p + 2], s3 = csr_src[r0 + p + 3];
      float w0 = s_w[h][p], w1 = s_w[h][p + 1], w2 = s_w[h][p + 2], w3 = s_w[h][p + 3];
      float x0 = xlh[(size_t)s0 * HC];
      float x1 = xlh[(size_t)s1 * HC];
      float x2 = xlh[(size_t)s2 * HC];
      float x3 = xlh[(size_t)s3 * HC];
      dn += (w0 + w1) + (w2 + w3);
      acc += w0 * x0 + w1 * x1 + w2 * x2 + w3 * x3;
    }
    for (; p < pj1; p++) {
      int s0 = csr_src[r0 + p];
      float w0 = s_w[h][p];
      dn += w0;
      acc += w0 * xlh[(size_t)s0 * HC];
    }
    s_v[h][j][lane] = acc / dn;
  }
  __syncthreads();

  // ---- phase 3: head-mean + bias + ELU ----
  int t = threadIdx.x;
  if (t < nnodes * CD) {
    int j = t >> 6, c = t & 63;
    float v = s_v[0][j][c] + s_v[1][j][c] + s_v[2][j][c] + s_v[3][j][c] + s_v[4][j][c];
    v = v * (1.0f / NH) + bias[c];
    v = v > 0.f ? v : expm1f(v);
    out[(size_t)(node0 + j) * CD + c] = v;
  }
}

extern "C" void kernel_launch(void* const* d_in, const int* in_sizes, int n_in,
                              void* d_out, int out_size, void* d_ws, size_t ws_size,
                              hipStream_t stream) {
  const float* x = (const float*)d_in[0];
  const int* ei = (const int*)d_in[1];      // [2, NE]: src row then dst row
  const float* eattr = (const float*)d_in[2];

  char* w = (char*)d_ws;
  int* degi      = (int*)w;                 w += NN * 4;
  int* cursor    = (int*)w;                 w += NN * 4;
  int* rowptr    = (int*)w;                 w += (NN + 1) * 4;
  int* csr_eid   = (int*)w;                 w += NE * 4;
  int* csr_src   = (int*)w;                 w += NE * 4;
  float* loop_attr = (float*)w;             w += (size_t)NN * ED * 4;
  float* ea_csr  = (float*)w;               w += (size_t)NE * ED * 4;
  float* xlA     = (float*)w;               w += (size_t)NN * HC * 4;
  float* hbuf    = (float*)w;               w += (size_t)NN * CD * 4;
  float* WeT     = (float*)w;               w += (size_t)3 * ED * HC * 4;

  const float* Wl0  = (const float*)d_in[3];
  const float* bl0  = (const float*)d_in[4];
  const float* att0 = (const float*)d_in[6];
  const float* b0   = (const float*)d_in[7];
  const float* Wl1  = (const float*)d_in[8];
  const float* bl1  = (const float*)d_in[9];
  const float* att1 = (const float*)d_in[11];
  const float* b1   = (const float*)d_in[12];
  const float* Wl2  = (const float*)d_in[13];
  const float* bl2  = (const float*)d_in[14];
  const float* att2 = (const float*)d_in[16];
  const float* b2   = (const float*)d_in[17];

  // graph structure + permuted edge attrs + WeT (layer-invariant)
  hipMemsetAsync(degi, 0, NN * 4, stream);
  hipMemsetAsync(cursor, 0, NN * 4, stream);
  k_count<<<(NE + 255) / 256, 256, 0, stream>>>(ei + NE, degi);
  k_scan<<<1, 1024, 0, stream>>>(degi, rowptr);
  k_fill<<<(NE + 255) / 256, 256, 0, stream>>>(ei, rowptr, cursor, csr_eid, csr_src);
  k_loopattr<<<(NN + 3) / 4, 256, 0, stream>>>(csr_eid, rowptr, eattr, loop_attr);
  k_eacsr<<<(NE * 4 + 255) / 256, 256, 0, stream>>>(csr_eid, eattr, ea_csr);
  k_wet3<<<(3 * ED * HC + 255) / 256, 256, 0, stream>>>(
      (const float*)d_in[5], (const float*)d_in[10], (const float*)d_in[15], WeT);

  // layer 0
  k_xl<ND><<<NN / 8, 320, 0, stream>>>(x, Wl0, bl0, xlA);
  k_fga<<<8 * SWZ, 320, 0, stream>>>(csr_src, rowptr, ea_csr, loop_attr,
                                     xlA, WeT, att0, b0, hbuf);
  // layer 1
  k_xl<CD><<<NN / 8, 320, 0, stream>>>(hbuf, Wl1, bl1, xlA);
  k_fga<<<8 * SWZ, 320, 0, stream>>>(csr_src, rowptr, ea_csr, loop_attr,
                                     xlA, WeT + ED * HC, att1, b1, hbuf);
  // layer 2
  k_xl<CD><<<NN / 8, 320, 0, stream>>>(hbuf, Wl2, bl2, xlA);
  k_fga<<<8 * SWZ, 320, 0, stream>>>(csr_src, rowptr, ea_csr, loop_attr,
                                     xlA, WeT + 2 * ED * HC, att2, b2, (float*)d_out);
}

// Round 15
// 627.351 us; speedup vs baseline: 1.8841x; 1.8841x over previous
//
#include <hip/hip_runtime.h>
#include <hip/hip_bf16.h>

// GATv2 x3 layers, MI355X. f32 in/out; edge_index int32.
// R15: R12 exactly (best: 528.7us), with ONE change: k_score uses
// 1024-thread blocks (16 waves/block) to probe whether per-CU wave packing
// was limiting gather-latency hiding (R12: occupancy 35% at VGPR=64 which
// permits 8 waves/SIMD). R14's score+agg fusion reverted (339us/layer:
// agg phase lost 3x TLP, no L1 reuse across the barrier).

#define NN 10000    // nodes
#define NE 200000   // edges
#define ND 128      // node dim (layer 0 input)
#define ED 16       // edge dim
#define CD 64       // conv dim (per head)
#define NH 5        // heads
#define HC 320      // NH*CD
#define EF 210000   // NE + NN (with self loops)
#define EFP 210048  // EF padded to 64
#define NEG 0.2f
#define SB2 26      // k_score blocks per XCD slice (8*26=208 blocks of 1024)

// ---- CSR build: count ----
__global__ void k_count(const int* __restrict__ dst, int* __restrict__ deg) {
  int e = blockIdx.x * blockDim.x + threadIdx.x;
  if (e >= NE) return;
  atomicAdd(&deg[dst[e]], 1);
}

// ---- CSR build: exclusive scan (single block, 1024 threads x 10 elems) ----
__global__ __launch_bounds__(1024) void k_scan(const int* __restrict__ deg,
                                               int* __restrict__ rowptr) {
  __shared__ int part[1024];
  int t = threadIdx.x;
  int base = t * 10;
  int local[10];
  int s = 0;
  #pragma unroll
  for (int j = 0; j < 10; j++) {
    int i = base + j;
    local[j] = (i < NN) ? deg[i] : 0;
    s += local[j];
  }
  part[t] = s;
  __syncthreads();
  for (int off = 1; off < 1024; off <<= 1) {
    int v = (t >= off) ? part[t - off] : 0;
    __syncthreads();
    part[t] += v;
    __syncthreads();
  }
  int prefix = (t > 0) ? part[t - 1] : 0;
  #pragma unroll
  for (int j = 0; j < 10; j++) {
    int i = base + j;
    if (i < NN) rowptr[i] = prefix;
    prefix += local[j];
  }
  if (t == 1023) rowptr[NN] = prefix;
}

// ---- CSR build: fill ----
__global__ void k_fill(const int* __restrict__ ei, const int* __restrict__ rowptr,
                       int* __restrict__ cursor, int* __restrict__ csr_eid,
                       int* __restrict__ csr_src, int* __restrict__ csr_dst) {
  int e = blockIdx.x * blockDim.x + threadIdx.x;
  if (e >= NE) return;
  int d = ei[NE + e];
  int slot = atomicAdd(&cursor[d], 1);
  int pos = rowptr[d] + slot;
  csr_eid[pos] = e;
  csr_src[pos] = ei[e];
  csr_dst[pos] = d;
}

// ---- loop_attr = mean of incoming edge_attr (gather, wave per node) ----
__global__ __launch_bounds__(256) void k_loopattr(const int* __restrict__ csr_eid,
                                                  const int* __restrict__ rowptr,
                                                  const float* __restrict__ eattr,
                                                  float* __restrict__ loop_attr) {
  int wave = threadIdx.x >> 6, lane = threadIdx.x & 63;
  int d = blockIdx.x * 4 + wave;
  if (d >= NN) return;
  int g = lane >> 4, k = lane & 15;
  int b = rowptr[d], n = rowptr[d + 1] - b;
  float s = 0.f;
  for (int i = g; i < n; i += 4)
    s += eattr[(size_t)csr_eid[b + i] * ED + k];
  s += __shfl_xor(s, 16, 64);
  s += __shfl_xor(s, 32, 64);
  if (g == 0) loop_attr[d * ED + k] = s / fmaxf((float)n, 1.0f);
}

// ---- ea_csr[p] = edge attrs permuted into CSR order (real edges only) ----
__global__ void k_eacsr(const int* __restrict__ csr_eid, const float* __restrict__ eattr,
                        float* __restrict__ ea_csr) {
  int idx = blockIdx.x * blockDim.x + threadIdx.x;  // (p, quad)
  if (idx >= NE * 4) return;
  int p = idx >> 2, q = idx & 3;
  const float4* sp = (const float4*)(eattr + (size_t)csr_eid[p] * ED);
  ((float4*)(ea_csr + (size_t)p * ED))[q] = sp[q];
}

// ---- WeT for all 3 layers in one dispatch ----
__global__ void k_wet3(const float* __restrict__ We0, const float* __restrict__ We1,
                       const float* __restrict__ We2, float* __restrict__ WeT) {
  int i = blockIdx.x * blockDim.x + threadIdx.x;
  if (i >= 3 * ED * HC) return;
  int l = i / (ED * HC), r = i % (ED * HC);
  int hc = r >> 4, k = r & 15;
  const float* src = (l == 0) ? We0 : (l == 1) ? We1 : We2;
  WeT[i] = src[k * HC + hc];
}

// ---- xl = h @ Wl + bl  (no LDS; h rows via uniform broadcast loads) ----
template <int D>
__global__ __launch_bounds__(320) void k_xl(const float* __restrict__ h,
                                            const float* __restrict__ Wl,
                                            const float* __restrict__ bl,
                                            float* __restrict__ xl) {
  constexpr int NPB = 8;
  int node0 = blockIdx.x * NPB;
  int t = threadIdx.x;  // output column 0..319
  float acc[NPB];
  #pragma unroll
  for (int i = 0; i < NPB; i++) acc[i] = 0.f;
  for (int k = 0; k < D; k += 4) {
    float w0 = Wl[(k + 0) * HC + t];
    float w1 = Wl[(k + 1) * HC + t];
    float w2 = Wl[(k + 2) * HC + t];
    float w3 = Wl[(k + 3) * HC + t];
    #pragma unroll
    for (int i = 0; i < NPB; i++) {
      float4 hv = *(const float4*)(h + (size_t)(node0 + i) * D + k);
      acc[i] += hv.x * w0 + hv.y * w1 + hv.z * w2 + hv.w * w3;
    }
  }
  float bv = bl[t];
  #pragma unroll
  for (int i = 0; i < NPB; i++)
    xl[(size_t)(node0 + i) * HC + t] = acc[i] + bv;
}

__device__ __forceinline__ float dot4(float4 a, float4 b) {
  return a.x * b.x + a.y * b.y + a.z * b.z + a.w * b.w;
}

// ---- scores: ONE THREAD PER (EDGE, HEAD); writes w = exp(clamped score).
// R12 thread body (unroll 4 -> VGPR~64, pipelined loads); 1024-thr blocks.
__global__ __launch_bounds__(1024) void k_score(
    const int* __restrict__ csr_src, const int* __restrict__ csr_dst,
    const float* __restrict__ ea_csr, const float* __restrict__ loop_attr,
    const float* __restrict__ xl, const float* __restrict__ WeT,
    const float* __restrict__ att, float* __restrict__ wP) {
  int bid = blockIdx.x;                       // 0..8*SB2-1
  int lb = (bid & 7) * SB2 + (bid >> 3);      // contiguous slice per XCD
  int p = lb * 1024 + threadIdx.x;
  if (p >= EF) return;
  int h = blockIdx.y;
  int s, d;
  const float* ea;
  if (p < NE) { s = csr_src[p]; d = csr_dst[p]; ea = ea_csr + (size_t)p * ED; }
  else        { s = d = p - NE; ea = loop_attr + (size_t)(p - NE) * ED; }
  float4 ea4[4];
  {
    const float4* q = (const float4*)ea;
    ea4[0] = q[0]; ea4[1] = q[1]; ea4[2] = q[2]; ea4[3] = q[3];
  }
  const float* xsrow = xl + (size_t)s * HC + h * CD;
  const float* xdrow = xl + (size_t)d * HC + h * CD;
  const float* wrow  = WeT + h * CD * ED;
  const float* arow  = att + h * CD;
  float sc = 0.f;
  #pragma unroll 4
  for (int cb = 0; cb < CD; cb += 4) {  // 16 iterations
    float4 xs4 = *(const float4*)(xsrow + cb);
    float4 xd4 = *(const float4*)(xdrow + cb);
    const float4* w0 = (const float4*)(wrow + (cb + 0) * ED);
    const float4* w1 = (const float4*)(wrow + (cb + 1) * ED);
    const float4* w2 = (const float4*)(wrow + (cb + 2) * ED);
    const float4* w3 = (const float4*)(wrow + (cb + 3) * ED);
    float z0 = xs4.x + xd4.x + dot4(ea4[0], w0[0]) + dot4(ea4[1], w0[1]) +
               dot4(ea4[2], w0[2]) + dot4(ea4[3], w0[3]);
    float z1 = xs4.y + xd4.y + dot4(ea4[0], w1[0]) + dot4(ea4[1], w1[1]) +
               dot4(ea4[2], w1[2]) + dot4(ea4[3], w1[3]);
    float z2 = xs4.z + xd4.z + dot4(ea4[0], w2[0]) + dot4(ea4[1], w2[1]) +
               dot4(ea4[2], w2[2]) + dot4(ea4[3], w2[3]);
    float z3 = xs4.w + xd4.w + dot4(ea4[0], w3[0]) + dot4(ea4[1], w3[1]) +
               dot4(ea4[2], w3[2]) + dot4(ea4[3], w3[3]);
    z0 *= (z0 > 0.f) ? 1.0f : NEG;
    z1 *= (z1 > 0.f) ? 1.0f : NEG;
    z2 *= (z2 > 0.f) ? 1.0f : NEG;
    z3 *= (z3 > 0.f) ? 1.0f : NEG;
    float4 a4 = *(const float4*)(arow + cb);
    sc += a4.x * z0 + a4.y * z1 + a4.z * z2 + a4.w * z3;
  }
  sc = fminf(fmaxf(sc, -60.f), 60.f);  // clamp never binds for sane inputs
  wP[(size_t)h * EFP + p] = __expf(sc);
}

// ---- aggregation: block per node, wave per head; single pass (no max/exp) --
__global__ __launch_bounds__(320) void k_agg(
    const int* __restrict__ csr_src, const int* __restrict__ rowptr,
    const float* __restrict__ wP, const float* __restrict__ xl,
    const float* __restrict__ bias, float* __restrict__ out) {
  __shared__ float s_v[NH][CD];
  int h = threadIdx.x >> 6, lane = threadIdx.x & 63;
  int d = blockIdx.x;
  int b = rowptr[d], n = rowptr[d + 1] - b;
  const float* sp = wP + (size_t)h * EFP;
  const float* xlh = xl + h * CD + lane;
  // self loop init
  float dn = sp[NE + d];
  float acc = dn * xlh[(size_t)d * HC];
  // edge loop, unroll 4 (uniform w addrs -> scalar loads)
  int p = b, pe = b + n;
  for (; p + 4 <= pe; p += 4) {
    int s0 = csr_src[p], s1 = csr_src[p + 1], s2 = csr_src[p + 2], s3 = csr_src[p + 3];
    float w0 = sp[p], w1 = sp[p + 1], w2 = sp[p + 2], w3 = sp[p + 3];
    float x0 = xlh[(size_t)s0 * HC];
    float x1 = xlh[(size_t)s1 * HC];
    float x2 = xlh[(size_t)s2 * HC];
    float x3 = xlh[(size_t)s3 * HC];
    dn += (w0 + w1) + (w2 + w3);
    acc += w0 * x0 + w1 * x1 + w2 * x2 + w3 * x3;
  }
  for (; p < pe; p++) {
    int s0 = csr_src[p];
    float w0 = sp[p];
    dn += w0;
    acc += w0 * xlh[(size_t)s0 * HC];
  }
  s_v[h][lane] = acc / dn;
  __syncthreads();
  if (h == 0) {
    float v = s_v[0][lane] + s_v[1][lane] + s_v[2][lane] + s_v[3][lane] + s_v[4][lane];
    v = v * (1.0f / NH) + bias[lane];
    v = v > 0.f ? v : expm1f(v);
    out[(size_t)d * CD + lane] = v;
  }
}

extern "C" void kernel_launch(void* const* d_in, const int* in_sizes, int n_in,
                              void* d_out, int out_size, void* d_ws, size_t ws_size,
                              hipStream_t stream) {
  const float* x = (const float*)d_in[0];
  const int* ei = (const int*)d_in[1];      // [2, NE]: src row then dst row
  const float* eattr = (const float*)d_in[2];

  char* w = (char*)d_ws;
  int* degi      = (int*)w;                 w += NN * 4;
  int* cursor    = (int*)w;                 w += NN * 4;
  int* rowptr    = (int*)w;                 w += (NN + 1) * 4;
  int* csr_eid   = (int*)w;                 w += NE * 4;
  int* csr_src   = (int*)w;                 w += NE * 4;
  int* csr_dst   = (int*)w;                 w += NE * 4;
  float* loop_attr = (float*)w;             w += (size_t)NN * ED * 4;
  float* ea_csr  = (float*)w;               w += (size_t)NE * ED * 4;
  float* xl      = (float*)w;               w += (size_t)NN * HC * 4;
  float* wPbuf   = (float*)w;               w += (size_t)NH * EFP * 4;
  float* WeT     = (float*)w;               w += (size_t)3 * ED * HC * 4;
  float* hbuf    = (float*)w;               w += (size_t)NN * CD * 4;

  // graph structure + permuted edge attrs + WeT (layer-invariant)
  hipMemsetAsync(degi, 0, NN * 4, stream);
  hipMemsetAsync(cursor, 0, NN * 4, stream);
  k_count<<<(NE + 255) / 256, 256, 0, stream>>>(ei + NE, degi);
  k_scan<<<1, 1024, 0, stream>>>(degi, rowptr);
  k_fill<<<(NE + 255) / 256, 256, 0, stream>>>(ei, rowptr, cursor, csr_eid, csr_src, csr_dst);
  k_loopattr<<<(NN + 3) / 4, 256, 0, stream>>>(csr_eid, rowptr, eattr, loop_attr);
  k_eacsr<<<(NE * 4 + 255) / 256, 256, 0, stream>>>(csr_eid, eattr, ea_csr);
  k_wet3<<<(3 * ED * HC + 255) / 256, 256, 0, stream>>>(
      (const float*)d_in[5], (const float*)d_in[10], (const float*)d_in[15], WeT);

  for (int l = 0; l < 3; l++) {
    const float* Wl  = (const float*)d_in[3 + 5 * l];
    const float* bl  = (const float*)d_in[4 + 5 * l];
    const float* att = (const float*)d_in[6 + 5 * l];
    const float* b   = (const float*)d_in[7 + 5 * l];

    if (l == 0) k_xl<ND><<<NN / 8, 320, 0, stream>>>(x, Wl, bl, xl);
    else        k_xl<CD><<<NN / 8, 320, 0, stream>>>(hbuf, Wl, bl, xl);

    dim3 gs(8 * SB2, NH);
    k_score<<<gs, 1024, 0, stream>>>(csr_src, csr_dst, ea_csr, loop_attr,
                                     xl, WeT + l * ED * HC, att, wPbuf);

    float* dst_out = (l < 2) ? hbuf : (float*)d_out;
    k_agg<<<NN, 320, 0, stream>>>(csr_src, rowptr, wPbuf, xl, b, dst_out);
  }
}